// Round 16
// baseline (1026.175 us; speedup 1.0000x reference)
//
#include <hip/hip_runtime.h>
#include <hip/hip_bf16.h>

typedef __attribute__((ext_vector_type(8))) short short8;
typedef __attribute__((ext_vector_type(8))) unsigned short ushort8;
typedef __attribute__((ext_vector_type(4))) float floatx4;
typedef __attribute__((ext_vector_type(16))) float floatx16;
typedef __attribute__((ext_vector_type(4))) unsigned int uint4v;
typedef __attribute__((ext_vector_type(2))) unsigned int uint2v;

#define DEVINL static __device__ __forceinline__

DEVINL float b2f(unsigned short s){ union{unsigned u; float f;} v; v.u=((unsigned)s)<<16; return v.f; }
DEVINL unsigned fbits(float f){ union{float f; unsigned u;} v; v.f=f; return v.u; }
DEVINL unsigned pack2(float f0, float f1){
  return __builtin_amdgcn_perm(fbits(f1)+0x8000u, fbits(f0)+0x8000u, 0x07060302u);
}
// single-instruction packed cvt (RNE), gfx950
DEVINL unsigned cvt_pk(float lo, float hi){
  unsigned r;
  asm("v_cvt_pk_bf16_f32 %0, %1, %2" : "=v"(r) : "v"(lo), "v"(hi));
  return r;
}
// tanh(x) = 1 - 2/(1+e^{2x}); exact limits at +-inf
DEVINL float tanh_fast(float v){
  float ex = __builtin_amdgcn_exp2f(v * 2.885390081777927f);   // e^{2v}
  return 1.f - 2.f*__builtin_amdgcn_rcpf(1.f + ex);
}

constexpr int Sc=256, Hc=768, Nc=128, HIDc=1024, Lc=16;

// ================= merged prep kernel =================
__global__ __launch_bounds__(256) void k_prep(const float* __restrict__ AH,
                                              const int* __restrict__ ST,
                                              const float* __restrict__ W1,
                                              const float* __restrict__ W2,
                                              unsigned short* __restrict__ con,
                                              unsigned short* __restrict__ w1mF,
                                              unsigned short* __restrict__ w2F2,
                                              unsigned short* __restrict__ wPQF){
  int bid = blockIdx.x, t = threadIdx.x;
  if (bid < 512) {
    int row = bid;                      // b*128 + n
    int b = row >> 7;
    int st = ST[row];
    const float* src = AH + ((size_t)(b*Sc + st))*Hc;
    unsigned short* dst = con + (size_t)row*Hc;
    if (t < 192) {
      float4 v = reinterpret_cast<const float4*>(src)[t];
      uint2v o = { pack2(v.x, v.y), pack2(v.z, v.w) };
      *reinterpret_cast<uint2v*>(dst + 4*t) = o;
    }
  } else if (bid < 896) {
    int sid = (bid - 512)*256 + t;      // 0..98303
    int l = sid & 63, kc = (sid >> 6) % 48, ht = sid / (48*64);
    int k = kc*16 + (l >> 5)*8;
    int h = ht*32 + (l & 31);
    const float* wp = W1 + (size_t)(2304 + k)*1024 + h;
    uint4v d;
    d[0] = pack2(wp[0],      wp[1024]);
    d[1] = pack2(wp[2*1024], wp[3*1024]);
    d[2] = pack2(wp[4*1024], wp[5*1024]);
    d[3] = pack2(wp[6*1024], wp[7*1024]);
    *reinterpret_cast<uint4v*>(w1mF + (size_t)sid*8) = d;
  } else if (bid < 912) {
    int gid = (bid - 896)*256 + t;      // 0..4095
    int l = gid & 63, chunk = gid >> 6;
    int row = l & 31, s = l >> 5;
    unsigned u[4];
    #pragma unroll
    for (int p = 0; p < 4; ++p) {
      int e0 = 2*p, e1 = 2*p + 1;
      int h0 = chunk*16 + 4*s + (e0 & 3) + 8*(e0 >> 2);
      int h1 = chunk*16 + 4*s + (e1 & 3) + 8*(e1 >> 2);
      float v0 = (row < 16) ? W2[(size_t)h0*Lc + row] : 0.f;
      float v1 = (row < 16) ? W2[(size_t)h1*Lc + row] : 0.f;
      u[p] = pack2(v0, v1);
    }
    uint4v d = { u[0], u[1], u[2], u[3] };
    *reinterpret_cast<uint4v*>(w2F2 + (size_t)gid*8) = d;
  } else {
    int sid = (bid - 912)*256 + t;      // 0..196607
    int lane = sid & 63, kcq = (sid >> 6) % 24, ht = sid / (24*64);
    int col = lane & 15, seg = lane >> 4;
    int hp = ht*16 + col;
    int kb = kcq*32 + seg*8;
    uint4v d;
    if (hp < 1024) {
      const float* w0 = W1 + (size_t)kb*1024 + hp;
      const float* wd = W1 + (size_t)(1536+kb)*1024 + hp;
      d[0] = pack2(w0[0]+wd[0],           w0[1024]+wd[1024]);
      d[1] = pack2(w0[2*1024]+wd[2*1024], w0[3*1024]+wd[3*1024]);
      d[2] = pack2(w0[4*1024]+wd[4*1024], w0[5*1024]+wd[5*1024]);
      d[3] = pack2(w0[6*1024]+wd[6*1024], w0[7*1024]+wd[7*1024]);
    } else {
      int hq = hp - 1024;
      const float* wc = W1 + (size_t)(768+kb)*1024 + hq;
      const float* wd = W1 + (size_t)(1536+kb)*1024 + hq;
      d[0] = pack2(wc[0]-wd[0],           wc[1024]-wd[1024]);
      d[1] = pack2(wc[2*1024]-wd[2*1024], wc[3*1024]-wd[3*1024]);
      d[2] = pack2(wc[4*1024]-wd[4*1024], wc[5*1024]-wd[5*1024]);
      d[3] = pack2(wc[6*1024]-wd[6*1024], wc[7*1024]-wd[7*1024]);
    }
    *reinterpret_cast<uint4v*>(wPQF + (size_t)sid*8) = d;
  }
}

// ---------------- P/Q via MFMA: out[512 rows][2048 cols] ----------------
__global__ __launch_bounds__(256) void k_pq(const unsigned short* __restrict__ con,
                                            const unsigned short* __restrict__ wPQF,
                                            float* __restrict__ P, float* __restrict__ Q){
  int rg = blockIdx.x >> 4, hg = blockIdx.x & 15;     // 16 rowgroups x 16 colgroups
  int t = threadIdx.x, w = t >> 6, lane = t & 63;
  int colh = lane & 15, rseg = lane >> 4;
  floatx4 zero = {0.f,0.f,0.f,0.f};
  floatx4 acc[2][2] = {{zero,zero},{zero,zero}};
  const unsigned short* a0p = con + (size_t)(rg*32 + colh)*Hc + rseg*8;
  const unsigned short* a1p = a0p + 16*Hc;
  const unsigned short* b0p = wPQF + (((size_t)((hg*8 + w*2)*24)) << 9) + (lane << 3);
  const unsigned short* b1p = b0p + (24 << 9);
  #pragma unroll
  for (int kc = 0; kc < 24; ++kc) {
    short8 af0 = *reinterpret_cast<const short8*>(a0p + kc*32);
    short8 af1 = *reinterpret_cast<const short8*>(a1p + kc*32);
    short8 bf0 = *reinterpret_cast<const short8*>(b0p + ((size_t)kc << 9));
    short8 bf1 = *reinterpret_cast<const short8*>(b1p + ((size_t)kc << 9));
    acc[0][0] = __builtin_amdgcn_mfma_f32_16x16x32_bf16(af0, bf0, acc[0][0], 0,0,0);
    acc[0][1] = __builtin_amdgcn_mfma_f32_16x16x32_bf16(af0, bf1, acc[0][1], 0,0,0);
    acc[1][0] = __builtin_amdgcn_mfma_f32_16x16x32_bf16(af1, bf0, acc[1][0], 0,0,0);
    acc[1][1] = __builtin_amdgcn_mfma_f32_16x16x32_bf16(af1, bf1, acc[1][1], 0,0,0);
  }
  #pragma unroll
  for (int m = 0; m < 2; ++m)
    #pragma unroll
    for (int n = 0; n < 2; ++n)
      #pragma unroll
      for (int rr = 0; rr < 4; ++rr) {
        int row = rg*32 + m*16 + rseg*4 + rr;
        int hp = hg*128 + w*32 + n*16 + colh;
        float val = acc[m][n][rr];
        if (hg < 8) P[(size_t)row*HIDc + hp] = val;
        else        Q[(size_t)row*HIDc + (hp - 1024)] = val;
      }
}

// ---------------- fused main kernel: one block per (b,i,jhalf) ----------------
// 3-WAVES/SIMD build: 1024 blocks x 768 threads (12 waves, 1 block/CU =
// 3 waves/SIMD, launch_bounds(768,3) caps ~170 regs). Phase A: 12 waves x
// 2ht x 2jt (acc 64) cover ht 0..23. Phase B: waves 0..7 x 1ht x 2jt cover
// ht 24..31. Each phase's GEMM2 partial goes to the 48KB LDS red buffer
// (per-wave rows; phase B does same-wave read-add-store). Barrier-free
// K-loop (r13 style: depth-2 wx prefetch, setprio on MFMA cluster).
__global__ __launch_bounds__(768, 3) void k_main(const unsigned short* __restrict__ con,
    const unsigned short* __restrict__ w1mF, const unsigned short* __restrict__ w2F2,
    const float* __restrict__ P, const float* __restrict__ Q, const float* __restrict__ b1,
    const float* __restrict__ b2v, float* __restrict__ out){
  __shared__ __align__(16) unsigned short conF[2*48*64*8];   // 96KB [jt][kc][lane][e]
  __shared__ __align__(16) float red[48][64][4];             // 48KB partial buffer
  __shared__ float Pi_lds[1024];

  // XCD-bijective decode: 8 XCDs each own one (b,jh)
  int bid = blockIdx.x;
  int xcd = bid & 7, i = bid >> 3;
  int b = xcd >> 1, jh = xcd & 1;
  int bi = b*128 + i, bN = b*128;
  int t = threadIdx.x, w = t >> 6, lane = t & 63;
  int col32 = lane & 31, hi5 = lane >> 5;

  // ---- stage Pi = P[i] + b1 (once) ----
  if (t < 256) {
    float4 p4 = reinterpret_cast<const float4*>(P + (size_t)(bN + i)*HIDc)[t];
    float4 b4 = reinterpret_cast<const float4*>(b1)[t];
    float4 s4 = { p4.x + b4.x, p4.y + b4.y, p4.z + b4.z, p4.w + b4.w };
    *reinterpret_cast<float4*>(&Pi_lds[4*t]) = s4;
  }
  // ---- stage conF once: 8 slots of 16B per thread ----
  {
    const unsigned short* conI = con + (size_t)(bN + i)*Hc;
    #pragma unroll
    for (int r = 0; r < 8; ++r) {
      int s = r*768 + t;                    // 0..6143
      int jt = (s >= 3072) ? 1 : 0;
      int rem = s - jt*3072;
      int kc = rem >> 6, ln = rem & 63;
      int j = jh*64 + jt*32 + (ln & 31);
      int kb = kc*16 + ((ln >> 5) << 3);
      ushort8 c8 = *reinterpret_cast<const ushort8*>(con + (size_t)(bN + j)*Hc + kb);
      ushort8 a8 = *reinterpret_cast<const ushort8*>(conI + kb);
      uint4v d;
      d[0] = cvt_pk(b2f(a8[0])*b2f(c8[0]), b2f(a8[1])*b2f(c8[1]));
      d[1] = cvt_pk(b2f(a8[2])*b2f(c8[2]), b2f(a8[3])*b2f(c8[3]));
      d[2] = cvt_pk(b2f(a8[4])*b2f(c8[4]), b2f(a8[5])*b2f(c8[5]));
      d[3] = cvt_pk(b2f(a8[6])*b2f(c8[6]), b2f(a8[7])*b2f(c8[7]));
      *reinterpret_cast<uint4v*>(conF + (size_t)s*8) = d;
    }
  }
  __syncthreads();

  const unsigned short* yb = conF + (lane << 3);
  constexpr size_t HTS = (size_t)48 << 9;   // w1mF ht stride (elems)
  constexpr size_t KCS = (size_t)1 << 9;    // kc stride (elems)
  constexpr size_t JTS = (size_t)48 << 9;   // conF jt stride

#define LOADW2(P0,P1, BASE, KC) { \
  size_t o_ = (size_t)((KC) < 48 ? (KC) : 47)*KCS; \
  P0 = *reinterpret_cast<const ushort8*>((BASE) + 0*HTS + o_); \
  P1 = *reinterpret_cast<const ushort8*>((BASE) + 1*HTS + o_); }
#define LOADW1(P0, BASE, KC) { \
  size_t o_ = (size_t)((KC) < 48 ? (KC) : 47)*KCS; \
  P0 = *reinterpret_cast<const ushort8*>((BASE) + o_); }
#define LOADY(Y0,Y1, KC) { \
  size_t o_ = (size_t)(KC)*KCS; \
  Y0 = *reinterpret_cast<const short8*>(yb + o_); \
  Y1 = *reinterpret_cast<const short8*>(yb + JTS + o_); }

// epilogue for one ht tile: tanh in-register -> 2 GEMM2 MFMAs into acc2_0/1
#define EPI(HTG, AJ0, AJ1) { \
  int htg = (HTG); \
  const unsigned short* w2p = w2F2 + (((size_t)(htg*2)) << 9) + (lane << 3); \
  ushort8 wf0 = *reinterpret_cast<const ushort8*>(w2p); \
  ushort8 wf1 = *reinterpret_cast<const ushort8*>(w2p + 512); \
  int hbase = htg*32 + 4*hi5; \
  _Pragma("unroll") \
  for (int jt = 0; jt < 2; ++jt) { \
    const floatx16& a = (jt==0) ? AJ0 : AJ1; \
    floatx16& a2 = (jt==0) ? acc2_0 : acc2_1; \
    const float* qrow = Q + (size_t)(bN + jh*64 + jt*32 + col32)*HIDc + hbase; \
    unsigned hfu[2][4]; \
    _Pragma("unroll") \
    for (int q = 0; q < 4; ++q) { \
      floatx4 qv = *reinterpret_cast<const floatx4*>(qrow + 8*q); \
      floatx4 pf = *reinterpret_cast<const floatx4*>(&Pi_lds[hbase + 8*q]); \
      float t0 = tanh_fast(a[q*4+0] + pf[0] + qv[0]); \
      float t1 = tanh_fast(a[q*4+1] + pf[1] + qv[1]); \
      float t2 = tanh_fast(a[q*4+2] + pf[2] + qv[2]); \
      float t3 = tanh_fast(a[q*4+3] + pf[3] + qv[3]); \
      hfu[q >> 1][(q & 1)*2 + 0] = cvt_pk(t0, t1); \
      hfu[q >> 1][(q & 1)*2 + 1] = cvt_pk(t2, t3); \
    } \
    union { uint4v u; short8 s; } f0, f1; \
    f0.u[0]=hfu[0][0]; f0.u[1]=hfu[0][1]; f0.u[2]=hfu[0][2]; f0.u[3]=hfu[0][3]; \
    f1.u[0]=hfu[1][0]; f1.u[1]=hfu[1][1]; f1.u[2]=hfu[1][2]; f1.u[3]=hfu[1][3]; \
    a2 = __builtin_amdgcn_mfma_f32_32x32x16_bf16(wf0, f0.s, a2, 0,0,0); \
    a2 = __builtin_amdgcn_mfma_f32_32x32x16_bf16(wf1, f1.s, a2, 0,0,0); \
  } }

  // ================= PHASE A: 12 waves x 2ht (ht 0..23) =================
  {
    const unsigned short* wpA = w1mF + (((size_t)(w*2)*48) << 9) + (lane << 3);
    floatx16 a00, a01, a10, a11;            // [ht][jt]
    #pragma unroll
    for (int r = 0; r < 16; ++r) { a00[r]=0.f; a01[r]=0.f; a10[r]=0.f; a11[r]=0.f; }

#define MFMA4A(U0,U1, Z0,Z1) { \
  __builtin_amdgcn_s_setprio(1); \
  a00 = __builtin_amdgcn_mfma_f32_32x32x16_bf16(U0, Z0, a00, 0,0,0); \
  a01 = __builtin_amdgcn_mfma_f32_32x32x16_bf16(U0, Z1, a01, 0,0,0); \
  a10 = __builtin_amdgcn_mfma_f32_32x32x16_bf16(U1, Z0, a10, 0,0,0); \
  a11 = __builtin_amdgcn_mfma_f32_32x32x16_bf16(U1, Z1, a11, 0,0,0); \
  __builtin_amdgcn_s_setprio(0); }

    ushort8 wa0,wa1, wb0,wb1;
    short8 y0,y1, z0,z1;
    LOADW2(wa0,wa1, wpA, 0);
    #pragma unroll
    for (int p = 0; p < 24; ++p) {
      LOADW2(wb0,wb1, wpA, 2*p+1);
      LOADY(y0,y1, 2*p);
      MFMA4A(wa0,wa1, y0,y1);
      LOADW2(wa0,wa1, wpA, 2*p+2);
      LOADY(z0,z1, 2*p+1);
      MFMA4A(wb0,wb1, z0,z1);
    }
#undef MFMA4A

    floatx16 acc2_0, acc2_1;
    #pragma unroll
    for (int r = 0; r < 16; ++r) { acc2_0[r] = 0.f; acc2_1[r] = 0.f; }
    EPI(w*2,     a00, a01);
    EPI(w*2 + 1, a10, a11);
    // store phase-A partials
    #pragma unroll
    for (int q = 0; q < 2; ++q) {
      floatx4 v0 = { acc2_0[q*4+0], acc2_0[q*4+1], acc2_0[q*4+2], acc2_0[q*4+3] };
      floatx4 v1 = { acc2_1[q*4+0], acc2_1[q*4+1], acc2_1[q*4+2], acc2_1[q*4+3] };
      *reinterpret_cast<floatx4*>(&red[w*4 + 0 + q][lane][0]) = v0;
      *reinterpret_cast<floatx4*>(&red[w*4 + 2 + q][lane][0]) = v1;
    }
  }

  // ================= PHASE B: waves 0..7 x 1ht (ht 24..31) =================
  if (w < 8) {
    const unsigned short* wpB = w1mF + (((size_t)((24 + w)*48)) << 9) + (lane << 3);
    floatx16 b0a, b1a;                      // [jt]
    #pragma unroll
    for (int r = 0; r < 16; ++r) { b0a[r]=0.f; b1a[r]=0.f; }

#define MFMA2B(U0, Z0,Z1) { \
  __builtin_amdgcn_s_setprio(1); \
  b0a = __builtin_amdgcn_mfma_f32_32x32x16_bf16(U0, Z0, b0a, 0,0,0); \
  b1a = __builtin_amdgcn_mfma_f32_32x32x16_bf16(U0, Z1, b1a, 0,0,0); \
  __builtin_amdgcn_s_setprio(0); }

    ushort8 wa0, wb0;
    short8 y0,y1, z0,z1;
    LOADW1(wa0, wpB, 0);
    #pragma unroll
    for (int p = 0; p < 24; ++p) {
      LOADW1(wb0, wpB, 2*p+1);
      LOADY(y0,y1, 2*p);
      MFMA2B(wa0, y0,y1);
      LOADW1(wa0, wpB, 2*p+2);
      LOADY(z0,z1, 2*p+1);
      MFMA2B(wb0, z0,z1);
    }
#undef MFMA2B

    floatx16 acc2_0, acc2_1;
    #pragma unroll
    for (int r = 0; r < 16; ++r) { acc2_0[r] = 0.f; acc2_1[r] = 0.f; }
    EPI(24 + w, b0a, b1a);
    // accumulate phase-B partials into same-wave rows (no cross-wave race)
    #pragma unroll
    for (int q = 0; q < 2; ++q) {
      floatx4 o0 = *reinterpret_cast<const floatx4*>(&red[w*4 + 0 + q][lane][0]);
      floatx4 o1 = *reinterpret_cast<const floatx4*>(&red[w*4 + 2 + q][lane][0]);
      #pragma unroll
      for (int c = 0; c < 4; ++c) { o0[c] += acc2_0[q*4+c]; o1[c] += acc2_1[q*4+c]; }
      *reinterpret_cast<floatx4*>(&red[w*4 + 0 + q][lane][0]) = o0;
      *reinterpret_cast<floatx4*>(&red[w*4 + 2 + q][lane][0]) = o1;
    }
  }
#undef EPI
#undef LOADW2
#undef LOADW1
#undef LOADY

  // ---- final cross-wave reduction ----
  __syncthreads();
  if (w < 4) {
    int jtR = w & 1, qR = w >> 1;
    floatx4 s = {0.f,0.f,0.f,0.f};
    #pragma unroll
    for (int src = 0; src < 12; ++src) {
      floatx4 v = *reinterpret_cast<const floatx4*>(&red[src*4 + jtR*2 + qR][lane][0]);
      s[0]+=v[0]; s[1]+=v[1]; s[2]+=v[2]; s[3]+=v[3];
    }
    int jout = jh*64 + jtR*32 + col32;
    int Lb = 8*qR + 4*hi5;
    float* op = out + ((size_t)bi*Nc + jout)*Lc + Lb;
    #pragma unroll
    for (int c = 0; c < 4; ++c) op[c] = s[c] + b2v[Lb + c];
  }
}

extern "C" void kernel_launch(void* const* d_in, const int* in_sizes, int n_in,
                              void* d_out, int out_size, void* d_ws, size_t ws_size,
                              hipStream_t stream) {
  const float* AH = (const float*)d_in[0];
  const int*   ST = (const int*)d_in[1];
  const float* W1 = (const float*)d_in[2];
  const float* b1 = (const float*)d_in[3];
  const float* W2 = (const float*)d_in[4];
  const float* b2 = (const float*)d_in[5];
  float* out = (float*)d_out;

  char* ws = (char*)d_ws;
  unsigned short* con  = (unsigned short*)ws;                //   786,432 B
  unsigned short* w1mF = (unsigned short*)(ws +   786432);   // 1,572,864 B
  unsigned short* wPQF = (unsigned short*)(ws +  2359296);   // 3,145,728 B
  float* P = (float*)(ws + 5505024);                         // 2,097,152 B
  float* Q = (float*)(ws + 7602176);                         // 2,097,152 B
  unsigned short* w2F2 = (unsigned short*)(ws + 9699328);    //    65,536 B

  k_prep<<<1680, 256, 0, stream>>>(AH, ST, W1, W2, con, w1mF, w2F2, wPQF);
  k_pq<<<256, 256, 0, stream>>>(con, wPQF, P, Q);
  k_main<<<1024, 768, 0, stream>>>(con, w1mF, w2F2, P, Q, b1, b2, out);
}